// Round 8
// baseline (114.072 us; speedup 1.0000x reference)
//
#include <hip/hip_runtime.h>
#include <cstdint>

// CapsuleLayer dynamic routing: B=256, R=1152, C=10, O=16, I=8, 3 iters.
// Round 8: XCD-aware block swizzle + de-spill.
//  * THEORY: the ~59us floor is the W-stream. 1280 blocks x 576KB W-slice
//    = 737 MB served from L3 (c-major blockIdx round-robins XCDs -> every
//    4MB XCD-L2 sees all 10 slices -> thrash). Swizzle swz=(bid&7)*160+
//    (bid>>3): each XCD gets 160 contiguous logical blocks = ~1.25 c's
//    -> W is L2-RESIDENT per XCD; L3 traffic 737MB -> ~10MB.
//  * r7's pv[12] preload spilled to scratch (WRITE_SIZE 160KB->15.4MB;
//    live range crossed barriers in runtime pass loop). REVERTED to
//    per-pass LDS reads (r6 proved them cheap: 61K conflict cycles).
//  * Kept r7 diet: v_pk_fma dots, select-two-then-one-cvtpk packing,
//    exp2 with log2e-folded weights, 1-ahead phase-1 prefetch.
// LDS [g][r][8] words, 73.7KB, 2 blocks/CU, 768 threads.
#define BB 256
#define RR 1152
#define CC 10
#define OO 16
#define II 8
#define NT 768
#define GG 2
#define NWAVE (NT / 64)    // 12
#define LOG2E 1.4426950408889634f

typedef float float2v __attribute__((ext_vector_type(2)));

__device__ __forceinline__ float bflo(uint32_t pk) {
    union { uint32_t i; float f; } a; a.i = pk << 16; return a.f;
}
__device__ __forceinline__ float bfhi(uint32_t pk) {
    union { uint32_t i; float f; } a; a.i = pk & 0xffff0000u; return a.f;
}
// dot4 via packed f32: 2 pk ops + 1 hadd
__device__ __forceinline__ float dot4pk(float4 a, float4 b) {
    float2v al = { a.x, a.y }, ah = { a.z, a.w };
    float2v bl = { b.x, b.y }, bh = { b.z, b.w };
    float2v h = __builtin_elementwise_fma(ah, bh, al * bl);
    return h.x + h.y;
}
// v + (value from lane l^1), DPP quad_perm [1,0,3,2] — VALU pipe
__device__ __forceinline__ float qpadd1(float v) {
    int o = __builtin_amdgcn_mov_dpp(__float_as_int(v), 0xB1, 0xF, 0xF, true);
    return v + __int_as_float(o);
}
// v + (value from lane l^2), DPP quad_perm [2,3,0,1]
__device__ __forceinline__ float qpadd2(float v) {
    int o = __builtin_amdgcn_mov_dpp(__float_as_int(v), 0x4E, 0xF, 0xF, true);
    return v + __int_as_float(o);
}
// value from lane l^2 (float), DPP quad_perm [2,3,0,1]
__device__ __forceinline__ float dppx2f(float v) {
    return __int_as_float(__builtin_amdgcn_mov_dpp(__float_as_int(v), 0x4E, 0xF, 0xF, true));
}
// packed bf16 pair from two f32 (hardware RNE), one instruction
__device__ __forceinline__ uint32_t cvtpk(float lo, float hi) {
    uint32_t r;
    asm("v_cvt_pk_bf16_f32 %0, %1, %2" : "=v"(r) : "v"(lo), "v"(hi));
    return r;
}
#if __has_builtin(__builtin_amdgcn_exp2f)
#define EXP2(x) __builtin_amdgcn_exp2f(x)
#else
#define EXP2(x) __expf((x) * 0.6931471805599453f)
#endif

__global__ __launch_bounds__(NT, 6)   // 6 waves/SIMD = 24 waves/CU
void k_caps(const float* __restrict__ x, const float* __restrict__ W,
            float* __restrict__ out) {
    extern __shared__ uint32_t u2[];          // [GG][RR][8] packed bf16 pairs
    __shared__ float part[NWAVE][17];         // wave index implies g (wv/6)
    __shared__ float p0s[NWAVE][8][4][GG];    // [wv][lane 2q][j][g]
    __shared__ float wsum[GG][OO];

    const int t = threadIdx.x;
    // XCD swizzle: XCD (bid%8) gets 160 contiguous logical blocks -> its
    // L2 sees only ~1.25 W-slices (W becomes L2-resident per XCD).
    const int bid = blockIdx.x;
    const int swz = (bid & 7) * (CC * (BB / GG) / 8) + (bid >> 3);
    const int c  = swz / (BB / GG);
    const int b0 = (swz % (BB / GG)) * GG;
    const int wv = t >> 6, l = t & 63;
    const int rg = t >> 3, p = t & 7;         // phase 1: 96 r-rows x 8 lanes

    uint32_t* uA = u2;                        // batch b0
    uint32_t* uB = u2 + (size_t)RR * 8;       // batch b0+1

    const int pos = (p >> 1) + ((p & 1) << 2);
    uint32_t* wrA = uA + (size_t)rg * 8 + pos;
    uint32_t* wrB = uB + (size_t)rg * 8 + pos;
    const bool pb0 = (p & 1) != 0, pb1 = (p & 2) != 0;

    // ---- Phase 1: u -> LDS; fused pass-0 sums; 1-ahead prefetch ----
    float s00 = 0.f, s01 = 0.f, s02 = 0.f, s03 = 0.f;
    float s10 = 0.f, s11 = 0.f, s12 = 0.f, s13 = 0.f;
    const float* wbase = W + ((size_t)rg * CC + c) * (OO * II) + p * 4;
    const float* xbase = x + ((size_t)b0 * RR + rg) * II + (p & 1) * 4;
    const size_t WSTEP = (size_t)96 * CC * OO * II;   // 122880 floats
    const size_t XSTEP = (size_t)96 * II;             // 768 floats
    float4 cw0 = *reinterpret_cast<const float4*>(wbase);
    float4 cw1 = *reinterpret_cast<const float4*>(wbase + 32);
    float4 cw2 = *reinterpret_cast<const float4*>(wbase + 64);
    float4 cw3 = *reinterpret_cast<const float4*>(wbase + 96);
    float4 cx0 = *reinterpret_cast<const float4*>(xbase);
    float4 cx1 = *reinterpret_cast<const float4*>(xbase + (size_t)RR * II);
#pragma unroll
    for (int it = 0; it < 12; ++it) {
        float4 w0 = cw0, w1 = cw1, w2 = cw2, w3 = cw3;
        float4 xh0 = cx0, xh1 = cx1;
        if (it < 11) {                        // issue next-iter loads first
            const float* nw = wbase + (size_t)(it + 1) * WSTEP;
            cw0 = *reinterpret_cast<const float4*>(nw);
            cw1 = *reinterpret_cast<const float4*>(nw + 32);
            cw2 = *reinterpret_cast<const float4*>(nw + 64);
            cw3 = *reinterpret_cast<const float4*>(nw + 96);
            const float* nx = xbase + (size_t)(it + 1) * XSTEP;
            cx0 = *reinterpret_cast<const float4*>(nx);
            cx1 = *reinterpret_cast<const float4*>(nx + (size_t)RR * II);
        }
        // ---- g = 0 ----
        {
            float d0 = qpadd1(dot4pk(w0, xh0));
            float d1 = qpadd1(dot4pk(w1, xh0));
            float d2 = qpadd1(dot4pk(w2, xh0));
            float d3 = qpadd1(dot4pk(w3, xh0));
            s00 += d0; s01 += d1; s02 += d2; s03 += d3;
            // own j = p&3; export j = (p&3)^2 (for xor2 partner's word)
            float sa = pb1 ? (pb0 ? d3 : d2) : (pb0 ? d1 : d0);
            float sb = pb1 ? (pb0 ? d1 : d0) : (pb0 ? d3 : d2);
            wrA[(size_t)it * 768] = cvtpk(sa, dppx2f(sb));
        }
        // ---- g = 1 ----
        {
            float e0 = qpadd1(dot4pk(w0, xh1));
            float e1 = qpadd1(dot4pk(w1, xh1));
            float e2 = qpadd1(dot4pk(w2, xh1));
            float e3 = qpadd1(dot4pk(w3, xh1));
            s10 += e0; s11 += e1; s12 += e2; s13 += e3;
            float sa = pb1 ? (pb0 ? e3 : e2) : (pb0 ? e1 : e0);
            float sb = pb1 ? (pb0 ? e1 : e0) : (pb0 ? e3 : e2);
            wrB[(size_t)it * 768] = cvtpk(sa, dppx2f(sb));
        }
    }
    // reduce pass-0 partials over the 8 r-groups of the wave (masks 8,16,32)
#pragma unroll
    for (int m = 8; m < 64; m <<= 1) {
        s00 += __shfl_xor(s00, m); s01 += __shfl_xor(s01, m);
        s02 += __shfl_xor(s02, m); s03 += __shfl_xor(s03, m);
        s10 += __shfl_xor(s10, m); s11 += __shfl_xor(s11, m);
        s12 += __shfl_xor(s12, m); s13 += __shfl_xor(s13, m);
    }
    if (l < 8) {          // lane l holds o = 4j + (l>>1); dup pairs harmless
        p0s[wv][l][0][0] = s00; p0s[wv][l][1][0] = s01;
        p0s[wv][l][2][0] = s02; p0s[wv][l][3][0] = s03;
        p0s[wv][l][0][1] = s10; p0s[wv][l][1][1] = s11;
        p0s[wv][l][2][1] = s12; p0s[wv][l][3][1] = s13;
    }
    __syncthreads();

    if (t < GG * OO) {   // g = t>>4, o = t&15 (wave 0)
        const int g = t >> 4, o = t & 15;
        float s = 0.f;
#pragma unroll
        for (int w = 0; w < NWAVE; ++w) s += p0s[w][2 * (o & 3)][o >> 2][g];
        s *= (1.0f / RR);                     // softmax(0) = 1/R
        float ss = s * s;                     // squash over 16-lane o-group
        ss += __shfl_xor(ss, 1); ss += __shfl_xor(ss, 2);
        ss += __shfl_xor(ss, 4); ss += __shfl_xor(ss, 8);
        wsum[g][o] = s * (ss / ((1.0f + ss) * sqrtf(ss + 1e-7f)));  // v0
    }
    __syncthreads();

    // ---- Phase 2: passes 1 and 2 from LDS; lane-quad owns one r ----
    const int g2 = wv / 6;                    // waves 0-5: g=0, waves 6-11: g=1
    const int wv6 = wv - g2 * 6;              // wave within the g-half
    const uint32_t* ug = g2 ? uB : uA;
    const int q = l & 3;                      // owns o in {2q,2q+1,2q+8,2q+9}
    const int rl = l >> 2;                    // 0..15
    const int rbase = wv6 * 16 + rl;
    const uint32_t* rp = ug + (size_t)rbase * 8 + 2 * q;   // words 2q,2q+1

    for (int pass = 1; pass < 3; ++pass) {
        // routing weights pre-scaled by log2(e): exp2(lg) == exp(raw)
        const float2v WQA = { wsum[g2][2 * q] * LOG2E,
                              wsum[g2][2 * q + 8] * LOG2E };
        const float2v WQB = { wsum[g2][2 * q + 1] * LOG2E,
                              wsum[g2][2 * q + 9] * LOG2E };
        float2v N0 = { 0.f, 0.f }, N1 = { 0.f, 0.f };
        float den = 0.f;

#pragma unroll
        for (int it2 = 0; it2 < 12; ++it2) {
            uint2 pp = *reinterpret_cast<const uint2*>(rp + (size_t)it2 * 768);
            // pp.x = row q (2q lo, 2q+1 hi); pp.y = row q+4 (2q+9 lo, 2q+8 hi)
            float2v P0 = { bflo(pp.x), bfhi(pp.y) };   // (u[2q],   u[2q+8])
            float2v P1 = { bfhi(pp.x), bflo(pp.y) };   // (u[2q+1], u[2q+9])
            float2v lg2 = __builtin_elementwise_fma(P0, WQA, P1 * WQB);
            float lg = lg2.x + lg2.y;
            lg = qpadd1(lg);                  // + lane^1 (quad partial)
            lg = qpadd2(lg);                  // + lane^2: full 16-o logit
            float e = EXP2(lg);               // == exp(raw logit)
            den += e;                         // same-q lanes hold distinct r's
            float2v E2 = { e, e };
            N0 = __builtin_elementwise_fma(E2, P0, N0);
            N1 = __builtin_elementwise_fma(E2, P1, N1);
        }

        float n0 = N0.x, n2 = N0.y, n1 = N1.x, n3 = N1.y;
#pragma unroll
        for (int m = 4; m < 64; m <<= 1) {
            n0 += __shfl_xor(n0, m); n1 += __shfl_xor(n1, m);
            n2 += __shfl_xor(n2, m); n3 += __shfl_xor(n3, m);
            den += __shfl_xor(den, m);
        }
        if (l < 4) {                          // lane l == q
            part[wv][2 * l]     = n0;
            part[wv][2 * l + 1] = n1;
            part[wv][2 * l + 8] = n2;
            part[wv][2 * l + 9] = n3;
            if (l == 0) part[wv][16] = den;   // each r counted exactly once
        }
        __syncthreads();

        if (t < GG * OO) {
            const int g = t >> 4, o = t & 15;
            float nf = 0.f, df = 0.f;
#pragma unroll
            for (int w = 0; w < 6; ++w) {
                nf += part[6 * g + w][o];
                df += part[6 * g + w][16];
            }
            float s = nf / df;
            float ss = s * s;
            ss += __shfl_xor(ss, 1); ss += __shfl_xor(ss, 2);
            ss += __shfl_xor(ss, 4); ss += __shfl_xor(ss, 8);
            float v = s * (ss / ((1.0f + ss) * sqrtf(ss + 1e-7f)));
            if (pass == 2)
                out[((size_t)(b0 + g) * CC + c) * OO + o] = v;
            else
                wsum[g][o] += v;
        }
        __syncthreads();
    }
}

extern "C" void kernel_launch(void* const* d_in, const int* in_sizes, int n_in,
                              void* d_out, int out_size, void* d_ws, size_t ws_size,
                              hipStream_t stream) {
    const float* x = (const float*)d_in[0];  // (B,R,I) fp32
    const float* W = (const float*)d_in[1];  // (R,C,O,I) fp32
    if (n_in >= 2 && in_sizes[0] == RR * CC * OO * II &&
        in_sizes[1] == BB * RR * II) {
        const float* tmp = x; x = W; W = tmp;
    }
    float* out = (float*)d_out;              // (B,1,C,O,1) fp32

    const size_t dyn_lds = (size_t)GG * RR * 8 * 4;   // 73,728 B
    k_caps<<<CC * (BB / GG), NT, dyn_lds, stream>>>(x, W, out);
}